// Round 1
// baseline (374.983 us; speedup 1.0000x reference)
//
#include <hip/hip_runtime.h>
#include <hip/hip_bf16.h>

#define BATCH 32
#define CIN   256
#define COUT  256
#define Hd    56
#define Wd    56
#define HW    (Hd*Wd)

typedef __attribute__((ext_vector_type(8))) short bf16x8;
typedef __attribute__((ext_vector_type(4))) float f32x4;

__device__ __forceinline__ unsigned short f2bf_rne(float f) {
    unsigned u = __builtin_bit_cast(unsigned, f);
    u += 0x7fffu + ((u >> 16) & 1u);
    return (unsigned short)(u >> 16);
}

// ---------------------------------------------------------------------------
// Prep: per permuted output channel n' (block), build
//   Wc[n'][k']  center-tap bf16 (k' = permuted input channel)
//   Wg[n'][t][j] off-center taps bf16 (t = 8 taps, j = in-channel within group)
//   bsum[n'] = sum_i b[n][i]
// permutation: n' = (n%4)*64 + n/4  <->  n = 4*(n'%64) + n'/64
// ---------------------------------------------------------------------------
__global__ void hetconv_prep(const float* __restrict__ W, const float* __restrict__ b,
                             unsigned short* __restrict__ Wc,
                             unsigned short* __restrict__ Wg,
                             float* __restrict__ bsum) {
    const int np = blockIdx.x;         // n' in [0,256)
    const int lane = threadIdx.x;      // 64 threads = 1 wave
    const int r = np >> 6;
    const int n = ((np & 63) << 2) | r;

    float s = 0.f;
    for (int i = lane; i < CIN; i += 64) s += b[n * CIN + i];
    #pragma unroll
    for (int off = 32; off > 0; off >>= 1) s += __shfl_down(s, off, 64);
    if (lane == 0) bsum[np] = s;

    for (int kp = lane; kp < CIN; kp += 64) {
        int i = ((kp & 63) << 2) | (kp >> 6);
        Wc[np * CIN + kp] = f2bf_rne(W[(n * CIN + i) * 9 + 4]);   // tap (1,1)
    }
    for (int u = lane; u < 8 * 64; u += 64) {
        int t = u >> 6, j = u & 63;
        int tap = t + (t >= 4);        // skip center
        int i = (j << 2) | r;          // i = 4j + r  (matches (i-n)%4==0)
        Wg[np * 512 + u] = f2bf_rne(W[(n * CIN + i) * 9 + tap]);
    }
}

// ---------------------------------------------------------------------------
// Main: block = (batch, 2-row tile). 8 waves = (row h in {0,1}) x (residue r).
// Two K-passes of 128 permuted channels staged in LDS as
//   [4 rows][64 cols][128 ch] bf16, octet-XOR-swizzled.
// Dense center part: all waves, K=256 total. Grouped off-center: wave r active
// in pass r>>1, K = 8 taps x 64 ch.  D tile per wave: 64 out-ch x 64 cols.
// ---------------------------------------------------------------------------
__global__ void hetconv_main(const float* __restrict__ x,
                             const unsigned short* __restrict__ Wc,
                             const unsigned short* __restrict__ Wg,
                             const float* __restrict__ bsum,
                             float* __restrict__ y) {
    __shared__ unsigned short xs[4 * 64 * 128];   // 64 KB

    const int bid = blockIdx.x;
    const int b   = bid / 28;
    const int R0  = (bid % 28) * 2;
    const int tid = threadIdx.x;
    const int lane = tid & 63;
    const int wid  = tid >> 6;
    const int h = wid & 1;           // output row within tile
    const int r = wid >> 1;          // out-channel residue group
    const int l15 = lane & 15;
    const int l4  = lane >> 4;

    f32x4 acc[4][4];
    #pragma unroll
    for (int i = 0; i < 4; ++i)
        #pragma unroll
        for (int j = 0; j < 4; ++j) acc[i][j] = f32x4{0.f, 0.f, 0.f, 0.f};

    const float* xb = x + (size_t)b * CIN * HW;

    for (int pass = 0; pass < 2; ++pass) {
        // ---- stage 128 permuted channels, rows R0-1..R0+2, cols 0..63 ----
        #pragma unroll
        for (int k = 0; k < 8; ++k) {
            int u = tid + (k << 9);
            int s = u & 255;               // spatial: row*64+col
            int g = u >> 8;                // pass-local channel octet [0,16)
            int row = s >> 6, col = s & 63;
            int grow = R0 - 1 + row;
            int kp0 = pass * 128 + g * 8;  // permuted channel base
            int rr = kp0 >> 6;             // input residue
            int j0 = kp0 & 63;
            bool ok = (grow >= 0) && (grow < Hd) && (col < Wd);
            const float* xp = xb + (size_t)grow * Wd + col;
            bf16x8 pk;
            #pragma unroll
            for (int e = 0; e < 8; ++e) {
                int ic = ((j0 + e) << 2) | rr;             // global channel
                float f = ok ? xp[(size_t)ic * HW] : 0.f;
                pk[e] = (short)f2bf_rne(f);
            }
            int addr = s * 256 + ((g ^ (s & 7)) << 4);
            *reinterpret_cast<bf16x8*>(reinterpret_cast<char*>(xs) + addr) = pk;
        }
        __syncthreads();

        // ---- dense center-tap GEMM: 4 K-steps of 32 channels ----
        {
            const int srow = (h + 1) * 64;
            #pragma unroll
            for (int ks = 0; ks < 4; ++ks) {
                bf16x8 a[4];
                #pragma unroll
                for (int mf = 0; mf < 4; ++mf) {
                    int m = r * 64 + mf * 16 + l15;
                    a[mf] = *reinterpret_cast<const bf16x8*>(
                        Wc + (size_t)m * 256 + pass * 128 + ks * 32 + l4 * 8);
                }
                #pragma unroll
                for (int nf = 0; nf < 4; ++nf) {
                    int s = srow + nf * 16 + l15;
                    int o = ks * 4 + l4;
                    int addr = s * 256 + ((o ^ (s & 7)) << 4);
                    bf16x8 bb = *reinterpret_cast<const bf16x8*>(
                        reinterpret_cast<const char*>(xs) + addr);
                    #pragma unroll
                    for (int mf = 0; mf < 4; ++mf)
                        acc[mf][nf] = __builtin_amdgcn_mfma_f32_16x16x32_bf16(
                            a[mf], bb, acc[mf][nf], 0, 0, 0);
                }
            }
        }

        // ---- grouped off-center taps (only this wave's residue channels) ----
        if ((r >> 1) == pass) {
            const int cbase = (r & 1) * 64;    // pass-local channel base
            #pragma unroll
            for (int t = 0; t < 8; ++t) {
                const int tap = t + (t >= 4);
                const int dy = tap / 3 - 1;
                const int dx = tap % 3 - 1;
                const int srow = (h + 1 + dy) * 64;
                #pragma unroll
                for (int ks2 = 0; ks2 < 2; ++ks2) {
                    bf16x8 a[4];
                    #pragma unroll
                    for (int mf = 0; mf < 4; ++mf) {
                        int m = r * 64 + mf * 16 + l15;
                        a[mf] = *reinterpret_cast<const bf16x8*>(
                            Wg + ((size_t)m * 8 + t) * 64 + ks2 * 32 + l4 * 8);
                    }
                    #pragma unroll
                    for (int nf = 0; nf < 4; ++nf) {
                        int c2 = nf * 16 + l15 + dx;
                        c2 = ((unsigned)c2 < 64u) ? c2 : 56;   // col 56 is all-zero pad
                        int s = srow + c2;
                        int o = ((cbase + ks2 * 32) >> 3) + l4;
                        int addr = s * 256 + ((o ^ (s & 7)) << 4);
                        bf16x8 bb = *reinterpret_cast<const bf16x8*>(
                            reinterpret_cast<const char*>(xs) + addr);
                        #pragma unroll
                        for (int mf = 0; mf < 4; ++mf)
                            acc[mf][nf] = __builtin_amdgcn_mfma_f32_16x16x32_bf16(
                                a[mf], bb, acc[mf][nf], 0, 0, 0);
                    }
                }
            }
        }
        __syncthreads();
    }

    // ---- epilogue: bias + store (un-permute output channel) ----
    const int gr = R0 + h;
    #pragma unroll
    for (int mf = 0; mf < 4; ++mf) {
        #pragma unroll
        for (int j = 0; j < 4; ++j) {
            int np = r * 64 + mf * 16 + l4 * 4 + j;
            int n  = ((np & 63) << 2) | r;
            float bias = bsum[np];
            float* yp = y + (((size_t)b * COUT + n) * Hd + gr) * Wd;
            #pragma unroll
            for (int nf = 0; nf < 4; ++nf) {
                int col = nf * 16 + l15;
                if (col < Wd) yp[col] = acc[mf][nf][j] + bias;
            }
        }
    }
}

extern "C" void kernel_launch(void* const* d_in, const int* in_sizes, int n_in,
                              void* d_out, int out_size, void* d_ws, size_t ws_size,
                              hipStream_t stream) {
    const float* x = (const float*)d_in[0];
    const float* W = (const float*)d_in[1];
    const float* b = (const float*)d_in[2];
    float* y = (float*)d_out;

    unsigned short* Wc   = (unsigned short*)d_ws;                       // 131072 B
    unsigned short* Wg   = (unsigned short*)((char*)d_ws + 131072);     // 262144 B
    float*          bsum = (float*)((char*)d_ws + 131072 + 262144);     // 1024 B

    hipLaunchKernelGGL(hetconv_prep, dim3(256), dim3(64), 0, stream, W, b, Wc, Wg, bsum);
    hipLaunchKernelGGL(hetconv_main, dim3(BATCH * 28), dim3(512), 0, stream, x, Wc, Wg, bsum, y);
}

// Round 2
// 202.569 us; speedup vs baseline: 1.8511x; 1.8511x over previous
//
#include <hip/hip_runtime.h>
#include <hip/hip_bf16.h>

#define BATCH 32
#define CIN   256
#define COUT  256
#define Hd    56
#define Wd    56
#define HW    (Hd*Wd)

typedef __attribute__((ext_vector_type(8))) short bf16x8;
typedef __attribute__((ext_vector_type(4))) float f32x4;

typedef const __attribute__((address_space(1))) void* gas1_t;
typedef __attribute__((address_space(3))) void* las3_t;

__device__ __forceinline__ unsigned short f2bf_rne(float f) {
    unsigned u = __builtin_bit_cast(unsigned, f);
    u += 0x7fffu + ((u >> 16) & 1u);
    return (unsigned short)(u >> 16);
}

// ---------------------------------------------------------------------------
// Weight prep: Wc[np][kp] center taps, Wg[np][t][j] off-center taps, bsum[np].
// permutation: np = (n%4)*64 + n/4 ; kp likewise for inputs.
// ---------------------------------------------------------------------------
__global__ void hetconv_prep(const float* __restrict__ W, const float* __restrict__ b,
                             unsigned short* __restrict__ Wc,
                             unsigned short* __restrict__ Wg,
                             float* __restrict__ bsum) {
    const int np = blockIdx.x;
    const int lane = threadIdx.x;
    const int r = np >> 6;
    const int n = ((np & 63) << 2) | r;

    float s = 0.f;
    for (int i = lane; i < CIN; i += 64) s += b[n * CIN + i];
    #pragma unroll
    for (int off = 32; off > 0; off >>= 1) s += __shfl_down(s, off, 64);
    if (lane == 0) bsum[np] = s;

    for (int kp = lane; kp < CIN; kp += 64) {
        int i = ((kp & 63) << 2) | (kp >> 6);
        Wc[np * CIN + kp] = f2bf_rne(W[(n * CIN + i) * 9 + 4]);
    }
    for (int u = lane; u < 8 * 64; u += 64) {
        int t = u >> 6, j = u & 63;
        int tap = t + (t >= 4);
        int i = (j << 2) | r;
        Wg[np * 512 + u] = f2bf_rne(W[(n * CIN + i) * 9 + tap]);
    }
}

// ---------------------------------------------------------------------------
// x convert: xb[b][pass2][row 58 (row 0 and 57 are zero pad)][col 64 (56-63
// zero)][128 ch bf16, octet-XOR-swizzled by col&7].  Octet g of pass p holds
// permuted channels kp = p*128 + g*8 + e, stored at octet slot g ^ (col&7).
// ---------------------------------------------------------------------------
__global__ __launch_bounds__(512) void hetconv_xconv(const float* __restrict__ x,
                                                     unsigned short* __restrict__ xb) {
    const int bid = blockIdx.x;
    const int b  = bid / 58;
    const int pr = bid % 58;
    const int tid = threadIdx.x;
    const int col = tid & 63;
    const int wid = tid >> 6;
    const int grow = pr - 1;
    const bool ok = (grow >= 0) && (grow < Hd) && (col < Wd);
    const float* xp = x + (size_t)b * CIN * HW + (size_t)grow * Wd + col;

    #pragma unroll
    for (int rd = 0; rd < 4; ++rd) {
        int octG = rd * 8 + wid;          // [0,32)
        int pass = octG >> 4;
        int g    = octG & 15;
        bf16x8 pk;
        #pragma unroll
        for (int e = 0; e < 8; ++e) {
            int kp = pass * 128 + g * 8 + e;
            int ic = ((kp & 63) << 2) | (kp >> 6);
            float f = ok ? xp[(size_t)ic * HW] : 0.f;
            pk[e] = (short)f2bf_rne(f);
        }
        size_t dst = ((size_t)(b * 2 + pass) * 58 + pr) * 8192
                   + col * 128 + ((g ^ (col & 7)) * 8);
        *reinterpret_cast<bf16x8*>(xb + dst) = pk;
    }
}

// ---------------------------------------------------------------------------
// Main: block = (batch, 2-row tile), 8 waves = (row h) x (residue r).
// Staging: linear 64KB slab copy via global_load_lds (swizzle pre-baked).
// Compute: identical MFMA structure to the verified R1 kernel.
// Epilogue: acc -> LDS -> coalesced float4 stores (448B per channel row-pair).
// ---------------------------------------------------------------------------
__global__ __launch_bounds__(512) void hetconv_main(const unsigned short* __restrict__ xb,
                             const unsigned short* __restrict__ Wc,
                             const unsigned short* __restrict__ Wg,
                             const float* __restrict__ bsum,
                             float* __restrict__ y) {
    __shared__ unsigned short xs[4 * 64 * 128];   // 64 KB

    const int bid = blockIdx.x;
    const int b   = bid / 28;
    const int R0  = (bid % 28) * 2;               // padded-row start (= image rows R0-1..R0+2)
    const int tid = threadIdx.x;
    const int lane = tid & 63;
    const int wid  = tid >> 6;
    const int h = wid & 1;
    const int r = wid >> 1;
    const int l15 = lane & 15;
    const int l4  = lane >> 4;

    f32x4 acc[4][4];
    #pragma unroll
    for (int i = 0; i < 4; ++i)
        #pragma unroll
        for (int j = 0; j < 4; ++j) acc[i][j] = f32x4{0.f, 0.f, 0.f, 0.f};

    for (int pass = 0; pass < 2; ++pass) {
        // ---- stage: 64 KB contiguous slab -> LDS, 8 x 16B per thread ----
        const unsigned short* slab = xb + ((size_t)(b * 2 + pass) * 58 + R0) * 8192;
        #pragma unroll
        for (int rd = 0; rd < 8; ++rd) {
            int vbase = rd * 512 + wid * 64;      // 16B-unit index, wave-uniform
            __builtin_amdgcn_global_load_lds(
                (gas1_t)(slab + (size_t)(vbase + lane) * 8),
                (las3_t)(xs + vbase * 8), 16, 0, 0);
        }
        __syncthreads();

        // ---- dense center-tap GEMM: 4 K-steps of 32 channels ----
        {
            const int srow = (h + 1) * 64;
            #pragma unroll
            for (int ks = 0; ks < 4; ++ks) {
                bf16x8 a[4];
                #pragma unroll
                for (int mf = 0; mf < 4; ++mf) {
                    int m = r * 64 + mf * 16 + l15;
                    a[mf] = *reinterpret_cast<const bf16x8*>(
                        Wc + (size_t)m * 256 + pass * 128 + ks * 32 + l4 * 8);
                }
                #pragma unroll
                for (int nf = 0; nf < 4; ++nf) {
                    int s = srow + nf * 16 + l15;
                    int o = ks * 4 + l4;
                    int addr = s * 256 + ((o ^ (s & 7)) << 4);
                    bf16x8 bb = *reinterpret_cast<const bf16x8*>(
                        reinterpret_cast<const char*>(xs) + addr);
                    #pragma unroll
                    for (int mf = 0; mf < 4; ++mf)
                        acc[mf][nf] = __builtin_amdgcn_mfma_f32_16x16x32_bf16(
                            a[mf], bb, acc[mf][nf], 0, 0, 0);
                }
            }
        }

        // ---- grouped off-center taps (this wave's residue channels) ----
        if ((r >> 1) == pass) {
            const int cbase = (r & 1) * 64;
            #pragma unroll
            for (int t = 0; t < 8; ++t) {
                const int tap = t + (t >= 4);
                const int dy = tap / 3 - 1;
                const int dx = tap % 3 - 1;
                const int srow = (h + 1 + dy) * 64;
                #pragma unroll
                for (int ks2 = 0; ks2 < 2; ++ks2) {
                    bf16x8 a[4];
                    #pragma unroll
                    for (int mf = 0; mf < 4; ++mf) {
                        int m = r * 64 + mf * 16 + l15;
                        a[mf] = *reinterpret_cast<const bf16x8*>(
                            Wg + ((size_t)m * 8 + t) * 64 + ks2 * 32 + l4 * 8);
                    }
                    #pragma unroll
                    for (int nf = 0; nf < 4; ++nf) {
                        int c2 = nf * 16 + l15 + dx;
                        c2 = ((unsigned)c2 < 64u) ? c2 : 56;   // col 56 is zero pad
                        int s = srow + c2;
                        int o = ((cbase + ks2 * 32) >> 3) + l4;
                        int addr = s * 256 + ((o ^ (s & 7)) << 4);
                        bf16x8 bb = *reinterpret_cast<const bf16x8*>(
                            reinterpret_cast<const char*>(xs) + addr);
                        #pragma unroll
                        for (int mf = 0; mf < 4; ++mf)
                            acc[mf][nf] = __builtin_amdgcn_mfma_f32_16x16x32_bf16(
                                a[mf], bb, acc[mf][nf], 0, 0, 0);
                    }
                }
            }
        }
        __syncthreads();
    }

    // ---- epilogue: acc -> LDS -> coalesced float4 stores ----
    float* lf = reinterpret_cast<float*>(xs);
    #pragma unroll
    for (int q = 0; q < 2; ++q) {
        if ((r >> 1) == q) {
            #pragma unroll
            for (int mf = 0; mf < 4; ++mf) {
                #pragma unroll
                for (int j = 0; j < 4; ++j) {
                    int chL = (r & 1) * 64 + mf * 16 + l4 * 4 + j;
                    float bias = bsum[q * 128 + chL];
                    #pragma unroll
                    for (int nf = 0; nf < 4; ++nf) {
                        int col = nf * 16 + l15;
                        if (col < Wd)
                            lf[chL * 116 + h * 56 + col] = acc[mf][nf][j] + bias;
                    }
                }
            }
        }
        __syncthreads();
        #pragma unroll
        for (int it = 0; it < 7; ++it) {
            int v = it * 512 + tid;            // [0, 3584): 128 chL x 28 float4
            int chL = v / 28;
            int f   = v % 28;
            int h2  = (f >= 14) ? 1 : 0;
            int colS = (f - h2 * 14) * 4;
            int n = ((chL & 63) << 2) | (q * 2 + (chL >> 6));
            f32x4 val = *reinterpret_cast<const f32x4*>(lf + chL * 116 + f * 4);
            // image rows: padded R0 maps to image rows R0-1..; outputs are rows R0-1+1+h2?
            // output rows for this block are gr = R0 + h2 - 0: waves computed rows R0+h (padded
            // center rows 1..2 of the slab) == image rows R0-1+1+h = R0+h. h2 matches h.
            *reinterpret_cast<f32x4*>(
                y + (((size_t)b * COUT + n) * Hd + (R0 + h2)) * Wd + colS) = val;
        }
        __syncthreads();
    }
}

extern "C" void kernel_launch(void* const* d_in, const int* in_sizes, int n_in,
                              void* d_out, int out_size, void* d_ws, size_t ws_size,
                              hipStream_t stream) {
    const float* x = (const float*)d_in[0];
    const float* W = (const float*)d_in[1];
    const float* b = (const float*)d_in[2];
    float* y = (float*)d_out;

    unsigned short* Wc   = (unsigned short*)d_ws;                        // 131072 B
    unsigned short* Wg   = (unsigned short*)((char*)d_ws + 131072);      // 262144 B
    float*          bsum = (float*)((char*)d_ws + 393216);               // 1024 B
    unsigned short* xb   = (unsigned short*)((char*)d_ws + 394240);      // 60,817,408 B

    hipLaunchKernelGGL(hetconv_prep,  dim3(256),        dim3(64),  0, stream, W, b, Wc, Wg, bsum);
    hipLaunchKernelGGL(hetconv_xconv, dim3(BATCH * 58), dim3(512), 0, stream, x, xb);
    hipLaunchKernelGGL(hetconv_main,  dim3(BATCH * 28), dim3(512), 0, stream, xb, Wc, Wg, bsum, y);
}